// Round 1
// baseline (586.802 us; speedup 1.0000x reference)
//
#include <hip/hip_runtime.h>
#include <math.h>

#define Bn 16
#define Cn 256
#define Hn 128
#define Wn 128
#define HWn (Hn * Wn)       // 16384
#define Rn 16               // C/16

// ---------------------------------------------------------------------------
// Pass 1: s[b,c] = mean over (h,w) of x[b,c,:,:].  One block per (b,c).
// ---------------------------------------------------------------------------
__global__ __launch_bounds__(256) void k_chan_mean(const float* __restrict__ x,
                                                   float* __restrict__ s) {
    int bc = blockIdx.x;  // 0..4095
    const float4* xp = (const float4*)(x + (size_t)bc * HWn);
    int t = threadIdx.x;
    float acc = 0.f;
#pragma unroll
    for (int i = 0; i < HWn / 4 / 256; ++i) {   // 16 iters of float4
        float4 v = xp[t + i * 256];
        acc += v.x + v.y + v.z + v.w;
    }
    for (int off = 32; off > 0; off >>= 1) acc += __shfl_down(acc, off, 64);
    __shared__ float wsum[4];
    if ((t & 63) == 0) wsum[t >> 6] = acc;
    __syncthreads();
    if (t == 0) {
        float tot = wsum[0] + wsum[1] + wsum[2] + wsum[3];
        s[bc] = tot * (1.0f / HWn);
    }
}

// ---------------------------------------------------------------------------
// Pass 2: gate[b,c] = sigmoid( relu(s @ W1) @ W2 ).  Single block.
// ---------------------------------------------------------------------------
__global__ __launch_bounds__(256) void k_gate(const float* __restrict__ s,
                                              const float* __restrict__ w1,
                                              const float* __restrict__ w2,
                                              float* __restrict__ gate) {
    __shared__ float sh_s[Bn * Cn];   // 16 KB
    __shared__ float sh_h[Bn * Rn];   // 1 KB
    int t = threadIdx.x;
    for (int i = t; i < Bn * Cn; i += 256) sh_s[i] = s[i];
    __syncthreads();
    {   // hidden = relu(s @ W1): 16*16 = 256 entries, one per thread
        int b = t / Rn, j = t % Rn;
        float acc = 0.f;
        for (int c = 0; c < Cn; ++c) acc += sh_s[b * Cn + c] * w1[c * Rn + j];
        sh_h[t] = fmaxf(acc, 0.f);
    }
    __syncthreads();
    for (int i = t; i < Bn * Cn; i += 256) {   // 16 outputs/thread
        int b = i / Cn, c = i % Cn;
        float acc = 0.f;
#pragma unroll
        for (int j = 0; j < Rn; ++j) acc += sh_h[b * Rn + j] * w2[j * Cn + c];
        gate[i] = 1.0f / (1.0f + expf(-acc));
    }
}

// ---------------------------------------------------------------------------
// Pass 3: m[b,p] = (1/C) * sum_c x[b,c,p] * gate[b,c].
// Grid: Bn * (HWn/1024) = 256 blocks; thread owns one float4 of pixels.
// ---------------------------------------------------------------------------
__global__ __launch_bounds__(256) void k_chan_reduce(const float* __restrict__ x,
                                                     const float* __restrict__ gate,
                                                     float* __restrict__ m) {
    const int chunks = HWn / 1024;              // 16
    int b = blockIdx.x / chunks;
    int chunk = blockIdx.x % chunks;
    int px4 = chunk * 256 + threadIdx.x;        // float4 index within hw
    __shared__ float g[Cn];
    for (int i = threadIdx.x; i < Cn; i += 256) g[i] = gate[b * Cn + i];
    __syncthreads();
    const float4* xb = (const float4*)(x + (size_t)b * Cn * HWn);
    float4 acc = {0.f, 0.f, 0.f, 0.f};
    for (int c = 0; c < Cn; ++c) {
        float4 v = xb[(size_t)c * (HWn / 4) + px4];
        float gv = g[c];
        acc.x += v.x * gv; acc.y += v.y * gv;
        acc.z += v.z * gv; acc.w += v.w * gv;
    }
    const float inv = 1.0f / Cn;
    float4 o = {acc.x * inv, acc.y * inv, acc.z * inv, acc.w * inv};
    ((float4*)(m + (size_t)b * HWn))[px4] = o;
}

// ---------------------------------------------------------------------------
// Pass 4: per-batch 3x3 zero-padded box sum of m, f = sigmoid(box/9),
// thr = w_i*var(f, ddof=1) + mean(f);  mask[b] = (1 > thr) ? 0 : 1.
// One block per batch.
// ---------------------------------------------------------------------------
__global__ __launch_bounds__(256) void k_mask(const float* __restrict__ m,
                                              const float* __restrict__ w_i,
                                              float* __restrict__ mask) {
    int b = blockIdx.x;
    const float* mb = m + (size_t)b * HWn;
    float sum = 0.f, sumsq = 0.f;
    for (int p = threadIdx.x; p < HWn; p += 256) {
        int i = p >> 7, j = p & (Wn - 1);
        float box = 0.f;
#pragma unroll
        for (int di = -1; di <= 1; ++di) {
            int ii = i + di;
            if (ii < 0 || ii >= Hn) continue;
#pragma unroll
            for (int dj = -1; dj <= 1; ++dj) {
                int jj = j + dj;
                if (jj < 0 || jj >= Wn) continue;
                box += mb[ii * Wn + jj];
            }
        }
        float f = 1.0f / (1.0f + expf(-box * (1.0f / 9.0f)));
        sum += f;
        sumsq += f * f;
    }
    for (int off = 32; off > 0; off >>= 1) {
        sum += __shfl_down(sum, off, 64);
        sumsq += __shfl_down(sumsq, off, 64);
    }
    __shared__ float red[8];
    int t = threadIdx.x;
    if ((t & 63) == 0) { red[t >> 6] = sum; red[4 + (t >> 6)] = sumsq; }
    __syncthreads();
    if (t == 0) {
        float S = red[0] + red[1] + red[2] + red[3];
        float Q = red[4] + red[5] + red[6] + red[7];
        const float n = (float)HWn;
        float mean = S / n;
        float var = (Q - S * S / n) / (n - 1.0f);
        float thr = w_i[0] * var + mean;
        mask[b] = (1.0f > thr) ? 0.0f : 1.0f;
    }
}

// ---------------------------------------------------------------------------
// Pass 5: out = x * gate[b,c] * mask[b].  mask==0 -> write zeros, skip x read.
// float4 grid-stride-free: exactly one float4 per thread.
// ---------------------------------------------------------------------------
__global__ __launch_bounds__(256) void k_out(const float* __restrict__ x,
                                             const float* __restrict__ gate,
                                             const float* __restrict__ mask,
                                             float* __restrict__ out) {
    size_t idx = (size_t)blockIdx.x * 256 + threadIdx.x;  // float4 index
    size_t e = idx << 2;                                  // element index
    int b = (int)(e >> 22);            // C*HW = 2^22
    int c = (int)((e >> 14) & 255);    // HW   = 2^14
    float mk = mask[b];                // wave-uniform within a block
    float4* op = (float4*)out;
    if (mk == 0.0f) {
        float4 z = {0.f, 0.f, 0.f, 0.f};
        op[idx] = z;
    } else {
        float4 v = ((const float4*)x)[idx];
        float g = gate[b * Cn + c] * mk;
        float4 o = {v.x * g, v.y * g, v.z * g, v.w * g};
        op[idx] = o;
    }
}

// ---------------------------------------------------------------------------
extern "C" void kernel_launch(void* const* d_in, const int* in_sizes, int n_in,
                              void* d_out, int out_size, void* d_ws, size_t ws_size,
                              hipStream_t stream) {
    const float* x    = (const float*)d_in[0];
    const float* w1   = (const float*)d_in[1];
    const float* w2   = (const float*)d_in[2];
    const float* w_i  = (const float*)d_in[3];
    float* out = (float*)d_out;

    // workspace layout (floats)
    float* ws   = (float*)d_ws;
    float* s    = ws;                       // 4096
    float* gate = ws + 4096;                // 4096
    float* m    = ws + 8192;                // 262144
    float* mask = ws + 8192 + Bn * HWn;     // 16

    k_chan_mean<<<Bn * Cn, 256, 0, stream>>>(x, s);
    k_gate<<<1, 256, 0, stream>>>(s, w1, w2, gate);
    k_chan_reduce<<<Bn * (HWn / 1024), 256, 0, stream>>>(x, gate, m);
    k_mask<<<Bn, 256, 0, stream>>>(m, w_i, mask);
    k_out<<<(Bn * Cn * HWn / 4) / 256, 256, 0, stream>>>(x, gate, mask, out);
}

// Round 2
// 540.094 us; speedup vs baseline: 1.0865x; 1.0865x over previous
//
#include <hip/hip_runtime.h>
#include <math.h>

#define Bn 16
#define Cn 256
#define Hn 128
#define Wn 128
#define HWn (Hn * Wn)       // 16384
#define Rn 16               // C/16
#define NG 4                // channel groups in pass 3
#define CG (Cn / NG)        // 64 channels per group

// ---------------------------------------------------------------------------
// Pass 1: s[b,c] = mean over (h,w) of x[b,c,:,:].  One block per (b,c).
// ---------------------------------------------------------------------------
__global__ __launch_bounds__(256) void k_chan_mean(const float* __restrict__ x,
                                                   float* __restrict__ s) {
    int bc = blockIdx.x;  // 0..4095
    const float4* xp = (const float4*)(x + (size_t)bc * HWn);
    int t = threadIdx.x;
    float acc = 0.f;
#pragma unroll
    for (int i = 0; i < HWn / 4 / 256; ++i) {   // 16 iters of float4
        float4 v = xp[t + i * 256];
        acc += v.x + v.y + v.z + v.w;
    }
    for (int off = 32; off > 0; off >>= 1) acc += __shfl_down(acc, off, 64);
    __shared__ float wsum[4];
    if ((t & 63) == 0) wsum[t >> 6] = acc;
    __syncthreads();
    if (t == 0) {
        float tot = wsum[0] + wsum[1] + wsum[2] + wsum[3];
        s[bc] = tot * (1.0f / HWn);
    }
}

// ---------------------------------------------------------------------------
// Pass 2: gate[b,c] = sigmoid( relu(s @ W1) @ W2 ).  Single block.
// ---------------------------------------------------------------------------
__global__ __launch_bounds__(256) void k_gate(const float* __restrict__ s,
                                              const float* __restrict__ w1,
                                              const float* __restrict__ w2,
                                              float* __restrict__ gate) {
    __shared__ float sh_s[Bn * Cn];   // 16 KB
    __shared__ float sh_h[Bn * Rn];   // 1 KB
    int t = threadIdx.x;
    for (int i = t; i < Bn * Cn; i += 256) sh_s[i] = s[i];
    __syncthreads();
    {   // hidden = relu(s @ W1): 16*16 = 256 entries, one per thread
        int b = t / Rn, j = t % Rn;
        float acc = 0.f;
        for (int c = 0; c < Cn; ++c) acc += sh_s[b * Cn + c] * w1[c * Rn + j];
        sh_h[t] = fmaxf(acc, 0.f);
    }
    __syncthreads();
    for (int i = t; i < Bn * Cn; i += 256) {   // 16 outputs/thread
        int b = i / Cn, c = i % Cn;
        float acc = 0.f;
#pragma unroll
        for (int j = 0; j < Rn; ++j) acc += sh_h[b * Rn + j] * w2[j * Cn + c];
        gate[i] = 1.0f / (1.0f + expf(-acc));
    }
}

// ---------------------------------------------------------------------------
// Pass 3: partial channel-weighted reduce.
// m_part[g][b][p] = (1/C) * sum_{c in group g} x[b,c,p] * gate[b,c]
// Grid: Bn * 16 chunks * NG groups = 1024 blocks (4 blocks/CU -> 16 waves/CU).
// Thread owns one float4 of pixels, loops CG=64 channels.
// ---------------------------------------------------------------------------
__global__ __launch_bounds__(256) void k_chan_reduce(const float* __restrict__ x,
                                                     const float* __restrict__ gate,
                                                     float* __restrict__ m_part) {
    int blk = blockIdx.x;
    int b = blk >> 6;               // 64 blocks per batch
    int g = (blk >> 4) & (NG - 1);  // channel group
    int chunk = blk & 15;           // pixel chunk (1024 px each)
    int px4 = chunk * 256 + threadIdx.x;  // float4 index within hw

    __shared__ float gg[CG];
    if (threadIdx.x < CG) gg[threadIdx.x] = gate[b * Cn + g * CG + threadIdx.x];
    __syncthreads();

    const float4* xb = (const float4*)(x + ((size_t)b * Cn + g * CG) * HWn);
    float4 acc = {0.f, 0.f, 0.f, 0.f};
#pragma unroll 8
    for (int c = 0; c < CG; ++c) {
        float4 v = xb[(size_t)c * (HWn / 4) + px4];
        float gv = gg[c];
        acc.x += v.x * gv; acc.y += v.y * gv;
        acc.z += v.z * gv; acc.w += v.w * gv;
    }
    const float inv = 1.0f / Cn;
    float4 o = {acc.x * inv, acc.y * inv, acc.z * inv, acc.w * inv};
    ((float4*)(m_part + ((size_t)g * Bn + b) * HWn))[px4] = o;
}

// ---------------------------------------------------------------------------
// Pass 4: combine partials into LDS, 3x3 zero-padded box sum, f=sigmoid(box/9),
// thr = w_i*var(f, ddof=1) + mean(f);  mask[b] = (1 > thr) ? 0 : 1.
// One block per batch; whole m[b] slab (64 KB) staged in LDS.
// ---------------------------------------------------------------------------
__global__ __launch_bounds__(256) void k_mask(const float* __restrict__ m_part,
                                              const float* __restrict__ w_i,
                                              float* __restrict__ mask) {
    __shared__ float sm[HWn];   // 64 KB
    int b = blockIdx.x;
    int t = threadIdx.x;
    const float* p0 = m_part + ((size_t)0 * Bn + b) * HWn;
    const float* p1 = m_part + ((size_t)1 * Bn + b) * HWn;
    const float* p2 = m_part + ((size_t)2 * Bn + b) * HWn;
    const float* p3 = m_part + ((size_t)3 * Bn + b) * HWn;
    for (int p = t; p < HWn; p += 256)
        sm[p] = p0[p] + p1[p] + p2[p] + p3[p];
    __syncthreads();

    float sum = 0.f, sumsq = 0.f;
    for (int p = t; p < HWn; p += 256) {
        int i = p >> 7, j = p & (Wn - 1);
        float box = 0.f;
#pragma unroll
        for (int di = -1; di <= 1; ++di) {
            int ii = i + di;
            if (ii < 0 || ii >= Hn) continue;
#pragma unroll
            for (int dj = -1; dj <= 1; ++dj) {
                int jj = j + dj;
                if (jj < 0 || jj >= Wn) continue;
                box += sm[ii * Wn + jj];
            }
        }
        float f = 1.0f / (1.0f + expf(-box * (1.0f / 9.0f)));
        sum += f;
        sumsq += f * f;
    }
    for (int off = 32; off > 0; off >>= 1) {
        sum += __shfl_down(sum, off, 64);
        sumsq += __shfl_down(sumsq, off, 64);
    }
    __shared__ float red[8];
    if ((t & 63) == 0) { red[t >> 6] = sum; red[4 + (t >> 6)] = sumsq; }
    __syncthreads();
    if (t == 0) {
        float S = red[0] + red[1] + red[2] + red[3];
        float Q = red[4] + red[5] + red[6] + red[7];
        const float n = (float)HWn;
        float mean = S / n;
        float var = (Q - S * S / n) / (n - 1.0f);
        float thr = w_i[0] * var + mean;
        mask[b] = (1.0f > thr) ? 0.0f : 1.0f;
    }
}

// ---------------------------------------------------------------------------
// Pass 5: out = x * gate[b,c] * mask[b].  mask==0 -> write zeros, skip x read.
// ---------------------------------------------------------------------------
__global__ __launch_bounds__(256) void k_out(const float* __restrict__ x,
                                             const float* __restrict__ gate,
                                             const float* __restrict__ mask,
                                             float* __restrict__ out) {
    size_t idx = (size_t)blockIdx.x * 256 + threadIdx.x;  // float4 index
    size_t e = idx << 2;                                  // element index
    int b = (int)(e >> 22);            // C*HW = 2^22
    int c = (int)((e >> 14) & 255);    // HW   = 2^14
    float mk = mask[b];                // wave-uniform within a block
    float4* op = (float4*)out;
    if (mk == 0.0f) {
        float4 z = {0.f, 0.f, 0.f, 0.f};
        op[idx] = z;
    } else {
        float4 v = ((const float4*)x)[idx];
        float g = gate[b * Cn + c] * mk;
        float4 o = {v.x * g, v.y * g, v.z * g, v.w * g};
        op[idx] = o;
    }
}

// ---------------------------------------------------------------------------
extern "C" void kernel_launch(void* const* d_in, const int* in_sizes, int n_in,
                              void* d_out, int out_size, void* d_ws, size_t ws_size,
                              hipStream_t stream) {
    const float* x    = (const float*)d_in[0];
    const float* w1   = (const float*)d_in[1];
    const float* w2   = (const float*)d_in[2];
    const float* w_i  = (const float*)d_in[3];
    float* out = (float*)d_out;

    // workspace layout (floats)
    float* ws     = (float*)d_ws;
    float* s      = ws;                          // 4096
    float* gate   = ws + 4096;                   // 4096
    float* m_part = ws + 8192;                   // NG*Bn*HWn = 1,048,576
    float* mask   = m_part + (size_t)NG * Bn * HWn;  // 16

    k_chan_mean<<<Bn * Cn, 256, 0, stream>>>(x, s);
    k_gate<<<1, 256, 0, stream>>>(s, w1, w2, gate);
    k_chan_reduce<<<Bn * 16 * NG, 256, 0, stream>>>(x, gate, m_part);
    k_mask<<<Bn, 256, 0, stream>>>(m_part, w_i, mask);
    k_out<<<(Bn * Cn * HWn / 4) / 256, 256, 0, stream>>>(x, gate, mask, out);
}

// Round 3
// 499.499 us; speedup vs baseline: 1.1748x; 1.0813x over previous
//
#include <hip/hip_runtime.h>
#include <math.h>

#define Bn 16
#define Cn 256
#define Hn 128
#define Wn 128
#define HWn (Hn * Wn)       // 16384
#define Rn 16               // C/16
#define NG 8                // channel groups in pass 3
#define CG (Cn / NG)        // 32 channels per group
#define NSTRIP 16           // row strips per batch in pass 4 (8 rows each)

// ---------------------------------------------------------------------------
// Pass 1: s[b,c] = mean over (h,w) of x[b,c,:,:].  One block per (b,c).
// ---------------------------------------------------------------------------
__global__ __launch_bounds__(256) void k_chan_mean(const float* __restrict__ x,
                                                   float* __restrict__ s) {
    int bc = blockIdx.x;  // 0..4095
    const float4* xp = (const float4*)(x + (size_t)bc * HWn);
    int t = threadIdx.x;
    float acc = 0.f;
#pragma unroll
    for (int i = 0; i < HWn / 4 / 256; ++i) {   // 16 iters of float4
        float4 v = xp[t + i * 256];
        acc += v.x + v.y + v.z + v.w;
    }
    for (int off = 32; off > 0; off >>= 1) acc += __shfl_down(acc, off, 64);
    __shared__ float wsum[4];
    if ((t & 63) == 0) wsum[t >> 6] = acc;
    __syncthreads();
    if (t == 0) {
        float tot = wsum[0] + wsum[1] + wsum[2] + wsum[3];
        s[bc] = tot * (1.0f / HWn);
    }
}

// ---------------------------------------------------------------------------
// Pass 2: gate[b,c] = sigmoid( relu(s @ W1) @ W2 ).  One block per batch.
// ---------------------------------------------------------------------------
__global__ __launch_bounds__(256) void k_gate(const float* __restrict__ s,
                                              const float* __restrict__ w1,
                                              const float* __restrict__ w2,
                                              float* __restrict__ gate) {
    __shared__ float sh_s[Cn];
    __shared__ float sh_h[Rn];
    __shared__ float red[256];
    int b = blockIdx.x, t = threadIdx.x;
    sh_s[t] = s[b * Cn + t];
    __syncthreads();
    {   // hidden j = t>>4, chunk k = t&15: partial dot of 16 elements
        int j = t >> 4, k = t & 15;
        float p = 0.f;
#pragma unroll
        for (int c = k * 16; c < k * 16 + 16; ++c) p += sh_s[c] * w1[c * Rn + j];
        red[t] = p;
    }
    __syncthreads();
    if (t < Rn) {
        float a = 0.f;
#pragma unroll
        for (int k = 0; k < 16; ++k) a += red[t * 16 + k];
        sh_h[t] = fmaxf(a, 0.f);
    }
    __syncthreads();
    float acc = 0.f;
#pragma unroll
    for (int j = 0; j < Rn; ++j) acc += sh_h[j] * w2[j * Cn + t];
    gate[b * Cn + t] = 1.0f / (1.0f + expf(-acc));
}

// ---------------------------------------------------------------------------
// Pass 3: partial channel-weighted reduce.
// m_part[g][b][p] = (1/C) * sum_{c in group g} x[b,c,p] * gate[b,c]
// Grid: Bn * NG * 16 chunks = 2048 blocks (8 blocks/CU -> 32 waves/CU).
// ---------------------------------------------------------------------------
__global__ __launch_bounds__(256) void k_chan_reduce(const float* __restrict__ x,
                                                     const float* __restrict__ gate,
                                                     float* __restrict__ m_part) {
    int blk = blockIdx.x;
    int b = blk >> 7;               // 128 blocks per batch
    int g = (blk >> 4) & (NG - 1);  // channel group
    int chunk = blk & 15;           // pixel chunk (1024 px each)
    int px4 = chunk * 256 + threadIdx.x;  // float4 index within hw

    __shared__ float gg[CG];
    if (threadIdx.x < CG) gg[threadIdx.x] = gate[b * Cn + g * CG + threadIdx.x];
    __syncthreads();

    const float4* xb = (const float4*)(x + ((size_t)b * Cn + g * CG) * HWn);
    float4 acc = {0.f, 0.f, 0.f, 0.f};
#pragma unroll 8
    for (int c = 0; c < CG; ++c) {
        float4 v = xb[(size_t)c * (HWn / 4) + px4];
        float gv = gg[c];
        acc.x += v.x * gv; acc.y += v.y * gv;
        acc.z += v.z * gv; acc.w += v.w * gv;
    }
    const float inv = 1.0f / Cn;
    float4 o = {acc.x * inv, acc.y * inv, acc.z * inv, acc.w * inv};
    ((float4*)(m_part + ((size_t)g * Bn + b) * HWn))[px4] = o;
}

// ---------------------------------------------------------------------------
// Pass 4: strip-parallel box-sum stats.
// Block = (b, strip of 8 rows). Stage 10 halo rows of m = sum of NG partials
// into LDS, compute f = sigmoid(box/9) per pixel, reduce sum/sumsq per strip.
// ---------------------------------------------------------------------------
__global__ __launch_bounds__(256) void k_boxpart(const float* __restrict__ m_part,
                                                 float* __restrict__ strip_s,
                                                 float* __restrict__ strip_q) {
    __shared__ float sm[10 * Wn];   // 5 KB: rows r0-1 .. r0+8
    int b = blockIdx.x >> 4;
    int st = blockIdx.x & (NSTRIP - 1);
    int r0 = st * 8;
    int t = threadIdx.x;

    for (int i = t; i < 10 * Wn; i += 256) {
        int row = r0 - 1 + (i >> 7);        // global row
        int col = i & (Wn - 1);
        float v = 0.f;
        if (row >= 0 && row < Hn) {
            size_t off = (size_t)row * Wn + col;
#pragma unroll
            for (int g = 0; g < NG; ++g)
                v += m_part[((size_t)g * Bn + b) * HWn + off];
        }
        sm[i] = v;
    }
    __syncthreads();

    float sum = 0.f, sumsq = 0.f;
    for (int pp = t; pp < 8 * Wn; pp += 256) {
        int lr = pp >> 7;               // 0..7 local row
        int col = pp & (Wn - 1);
        float box = 0.f;
#pragma unroll
        for (int di = 0; di < 3; ++di) {
            const float* row = sm + (lr + di) * Wn;
            float mid = row[col];
            float lft = (col > 0) ? row[col - 1] : 0.f;
            float rgt = (col < Wn - 1) ? row[col + 1] : 0.f;
            box += mid + lft + rgt;
        }
        float f = 1.0f / (1.0f + expf(-box * (1.0f / 9.0f)));
        sum += f;
        sumsq += f * f;
    }
    for (int off = 32; off > 0; off >>= 1) {
        sum += __shfl_down(sum, off, 64);
        sumsq += __shfl_down(sumsq, off, 64);
    }
    __shared__ float red[8];
    if ((t & 63) == 0) { red[t >> 6] = sum; red[4 + (t >> 6)] = sumsq; }
    __syncthreads();
    if (t == 0) {
        strip_s[blockIdx.x] = red[0] + red[1] + red[2] + red[3];
        strip_q[blockIdx.x] = red[4] + red[5] + red[6] + red[7];
    }
}

// ---------------------------------------------------------------------------
// Pass 5: out = x * gate[b,c] * mask[b]; mask computed inline from strip
// partials. mask==0 -> write zeros, skip x read.
// Grid: 8192 blocks; each block = 2048 float4 (8 per thread), b uniform.
// ---------------------------------------------------------------------------
__global__ __launch_bounds__(256) void k_out(const float* __restrict__ x,
                                             const float* __restrict__ gate,
                                             const float* __restrict__ strip_s,
                                             const float* __restrict__ strip_q,
                                             const float* __restrict__ w_i,
                                             float* __restrict__ out) {
    int b = blockIdx.x >> 9;            // 512 blocks per batch
    __shared__ float sh_mask;
    if (threadIdx.x == 0) {
        float S = 0.f, Q = 0.f;
#pragma unroll
        for (int st = 0; st < NSTRIP; ++st) {
            S += strip_s[b * NSTRIP + st];
            Q += strip_q[b * NSTRIP + st];
        }
        const float n = (float)HWn;
        float mean = S / n;
        float var = (Q - S * S / n) / (n - 1.0f);
        float thr = w_i[0] * var + mean;
        sh_mask = (1.0f > thr) ? 0.0f : 1.0f;
    }
    __syncthreads();
    float mk = sh_mask;

    size_t base = (size_t)blockIdx.x * 2048 + threadIdx.x;  // float4 index
    float4* op = (float4*)out;
    if (mk == 0.0f) {
        float4 z = {0.f, 0.f, 0.f, 0.f};
#pragma unroll
        for (int i = 0; i < 8; ++i) op[base + i * 256] = z;
    } else {
#pragma unroll
        for (int i = 0; i < 8; ++i) {
            size_t idx = base + i * 256;
            float4 v = ((const float4*)x)[idx];
            int c = (int)((idx >> 12) & 255);   // (idx*4)>>14
            float g = gate[b * Cn + c] * mk;
            float4 o = {v.x * g, v.y * g, v.z * g, v.w * g};
            op[idx] = o;
        }
    }
}

// ---------------------------------------------------------------------------
extern "C" void kernel_launch(void* const* d_in, const int* in_sizes, int n_in,
                              void* d_out, int out_size, void* d_ws, size_t ws_size,
                              hipStream_t stream) {
    const float* x    = (const float*)d_in[0];
    const float* w1   = (const float*)d_in[1];
    const float* w2   = (const float*)d_in[2];
    const float* w_i  = (const float*)d_in[3];
    float* out = (float*)d_out;

    // workspace layout (floats)
    float* ws      = (float*)d_ws;
    float* s       = ws;                              // 4096
    float* gate    = ws + 4096;                       // 4096
    float* m_part  = ws + 8192;                       // NG*Bn*HWn = 2,097,152
    float* strip_s = m_part + (size_t)NG * Bn * HWn;  // 256
    float* strip_q = strip_s + Bn * NSTRIP;           // 256

    k_chan_mean<<<Bn * Cn, 256, 0, stream>>>(x, s);
    k_gate<<<Bn, 256, 0, stream>>>(s, w1, w2, gate);
    k_chan_reduce<<<Bn * NG * 16, 256, 0, stream>>>(x, gate, m_part);
    k_boxpart<<<Bn * NSTRIP, 256, 0, stream>>>(m_part, strip_s, strip_q);
    k_out<<<8192, 256, 0, stream>>>(x, gate, strip_s, strip_q, w_i, out);
}